// Round 3
// baseline (966.829 us; speedup 1.0000x reference)
//
#include <hip/hip_runtime.h>
#include <hip/hip_bf16.h>
#include <cmath>

#define S_LEN 2048
#define DDIM  2048
#define NHEAD 16
#define HDIM  128
#define BATCH 4
#define KPAD  152  // K LDS row: 128 + 24
#define VPAD  40   // V LDS row: 32 + 8
#define PPAD  40   // P LDS row: 32 + 8

typedef __bf16 bf16;
typedef __attribute__((ext_vector_type(8))) __bf16 bf16x8;
typedef __attribute__((ext_vector_type(4))) __bf16 bf16x4;
typedef __attribute__((ext_vector_type(4))) float  f32x4;

__device__ __forceinline__ void gl_lds(const bf16* g, bf16* l) {
  __builtin_amdgcn_global_load_lds((const __attribute__((address_space(1))) unsigned*)g,
                                   (__attribute__((address_space(3))) unsigned*)l, 16, 0, 0);
}

__global__ __launch_bounds__(256)
void conv_kernel(const float* __restrict__ x, bf16* __restrict__ y) {
  size_t i = ((size_t)blockIdx.x * 256 + threadIdx.x) * 8;
  float4 a = *(const float4*)&x[i];
  float4 b = *(const float4*)&x[i + 4];
  bf16x8 o;
  o[0] = (bf16)a.x; o[1] = (bf16)a.y; o[2] = (bf16)a.z; o[3] = (bf16)a.w;
  o[4] = (bf16)b.x; o[5] = (bf16)b.y; o[6] = (bf16)b.z; o[7] = (bf16)b.w;
  *(bf16x8*)&y[i] = o;
}

// W f32 [2048][2048] -> Wt bf16 [n][k]
__global__ __launch_bounds__(256)
void twconv_kernel(const float* __restrict__ W, bf16* __restrict__ Wt) {
  __shared__ bf16 tile[64][72];
  const int t  = threadIdx.x;
  const int k0 = blockIdx.x * 64;
  const int n0 = blockIdx.y * 64;
#pragma unroll
  for (int it = 0; it < 4; it++) {
    int k = (t >> 4) + it * 16;
    int n = (t & 15) * 4;
    float4 v = *(const float4*)&W[(size_t)(k0 + k) * DDIM + n0 + n];
    tile[k][n + 0] = (bf16)v.x; tile[k][n + 1] = (bf16)v.y;
    tile[k][n + 2] = (bf16)v.z; tile[k][n + 3] = (bf16)v.w;
  }
  __syncthreads();
#pragma unroll
  for (int it = 0; it < 2; it++) {
    int n  = (t >> 3) + it * 32;
    int kc = (t & 7) * 8;
    bf16x8 o;
#pragma unroll
    for (int j = 0; j < 8; j++) o[j] = tile[kc + j][n];
    *(bf16x8*)&Wt[(size_t)(n0 + n) * DDIM + k0 + kc] = o;
  }
}

// 256x256-tile GEMM, BK=64, 8 waves (2M x 4N), double-buffered LDS (128 KiB),
// counted vmcnt(8): next tile's global_load_lds stay in flight across barriers.
// Chunked XCD swizzle: XCD k (assuming dispatch = linear%8) gets a contiguous
// 1024-row M-band (4 MB A-panel, fits one L2) x all N.
// MODE: 0=Q(RoPE+scale), 1=K(RoPE), 2=V(transposed [b][n][h][s]), 3=OUT(f32)
template <int MODE>
__global__ __launch_bounds__(512, 2)
void gemm_kernel(const bf16* __restrict__ A, const bf16* __restrict__ Bt,
                 void* __restrict__ Out) {
  __shared__ bf16 As[2][256 * 64];
  __shared__ bf16 Bs[2][256 * 64];

  const int t    = threadIdx.x;
  const int lin    = blockIdx.y * 8 + blockIdx.x;       // 0..255
  const int newlin = (lin & 7) * 32 + (lin >> 3);       // bijective chunked remap
  const int m0   = (newlin >> 3) * 256;
  const int n0   = (newlin & 7) * 256;
  const int lane = t & 63;
  const int wave = t >> 6;          // 0..7
  const int wm   = wave >> 2;       // 0..1  (M half)
  const int wn   = wave & 3;        // 0..3  (N quarter)
  const int quad = lane >> 4;
  const int lm   = lane & 15;
  const int sw   = lm & 7;

  const int lrow   = lane >> 3;     // 0..7
  const int lslot  = lane & 7;
  const int lchunk = lslot ^ lrow;  // pre-swizzled global chunk

  const int rA = wm * 128 + wn * 32;
  const int rB = (wn >> 1) * 128 + (wm * 2 + (wn & 1)) * 32;
  const bf16* gA = &A [(size_t)(m0 + rA + lrow) * DDIM + lchunk * 8];
  const bf16* gB = &Bt[(size_t)(n0 + rB + lrow) * DDIM + lchunk * 8];

  f32x4 acc[8][4];
#pragma unroll
  for (int i = 0; i < 8; i++)
#pragma unroll
    for (int j = 0; j < 4; j++) acc[i][j] = (f32x4){0.f, 0.f, 0.f, 0.f};

  auto stage = [&](int k0, int b) {
#pragma unroll
    for (int q = 0; q < 4; q++) {
      gl_lds(gA + (size_t)q * 8 * DDIM + k0, &As[b][(rA + q * 8) * 64]);
      gl_lds(gB + (size_t)q * 8 * DDIM + k0, &Bs[b][(rB + q * 8) * 64]);
    }
  };

  stage(0, 0);
  stage(64, 1);
  asm volatile("s_waitcnt vmcnt(8)" ::: "memory");  // tile 0 landed; tile 1 in flight
  __builtin_amdgcn_s_barrier();

  const int NT = DDIM / 64;  // 32
#pragma unroll 2
  for (int tt = 0; tt < NT; ++tt) {
    const bf16* as = &As[tt & 1][0];
    const bf16* bs = &Bs[tt & 1][0];
    bf16x8 af[4], bfr[4];

    // phase 0: K-slice 0, M-half 0
#pragma unroll
    for (int j = 0; j < 4; j++)
      bfr[j] = *(const bf16x8*)&bs[(wn * 64 + j * 16 + lm) * 64 + 8 * (quad ^ sw)];
#pragma unroll
    for (int i = 0; i < 4; i++)
      af[i] = *(const bf16x8*)&as[(wm * 128 + i * 16 + lm) * 64 + 8 * (quad ^ sw)];
    __builtin_amdgcn_s_setprio(1);
#pragma unroll
    for (int i = 0; i < 4; i++)
#pragma unroll
      for (int j = 0; j < 4; j++)
        acc[i][j] = __builtin_amdgcn_mfma_f32_16x16x32_bf16(af[i], bfr[j], acc[i][j], 0, 0, 0);
    __builtin_amdgcn_s_setprio(0);
    __builtin_amdgcn_sched_barrier(0);

    // phase 1: K-slice 0, M-half 1 (reuses bfr)
#pragma unroll
    for (int i = 0; i < 4; i++)
      af[i] = *(const bf16x8*)&as[(wm * 128 + 64 + i * 16 + lm) * 64 + 8 * (quad ^ sw)];
    __builtin_amdgcn_s_setprio(1);
#pragma unroll
    for (int i = 0; i < 4; i++)
#pragma unroll
      for (int j = 0; j < 4; j++)
        acc[4 + i][j] = __builtin_amdgcn_mfma_f32_16x16x32_bf16(af[i], bfr[j], acc[4 + i][j], 0, 0, 0);
    __builtin_amdgcn_s_setprio(0);
    __builtin_amdgcn_sched_barrier(0);

    // phase 2: K-slice 1, M-half 0
#pragma unroll
    for (int j = 0; j < 4; j++)
      bfr[j] = *(const bf16x8*)&bs[(wn * 64 + j * 16 + lm) * 64 + 8 * ((4 + quad) ^ sw)];
#pragma unroll
    for (int i = 0; i < 4; i++)
      af[i] = *(const bf16x8*)&as[(wm * 128 + i * 16 + lm) * 64 + 8 * ((4 + quad) ^ sw)];
    __builtin_amdgcn_s_setprio(1);
#pragma unroll
    for (int i = 0; i < 4; i++)
#pragma unroll
      for (int j = 0; j < 4; j++)
        acc[i][j] = __builtin_amdgcn_mfma_f32_16x16x32_bf16(af[i], bfr[j], acc[i][j], 0, 0, 0);
    __builtin_amdgcn_s_setprio(0);
    __builtin_amdgcn_sched_barrier(0);

    // phase 3: K-slice 1, M-half 1
#pragma unroll
    for (int i = 0; i < 4; i++)
      af[i] = *(const bf16x8*)&as[(wm * 128 + 64 + i * 16 + lm) * 64 + 8 * ((4 + quad) ^ sw)];
    __builtin_amdgcn_s_setprio(1);
#pragma unroll
    for (int i = 0; i < 4; i++)
#pragma unroll
      for (int j = 0; j < 4; j++)
        acc[4 + i][j] = __builtin_amdgcn_mfma_f32_16x16x32_bf16(af[i], bfr[j], acc[4 + i][j], 0, 0, 0);
    __builtin_amdgcn_s_setprio(0);
    __builtin_amdgcn_sched_barrier(0);

    // tile boundary: free buf[tt&1], keep tile tt+1's loads in flight
    asm volatile("s_waitcnt lgkmcnt(0)" ::: "memory");
    __builtin_amdgcn_s_barrier();                  // all waves done reading buf[tt&1]
    if (tt + 2 < NT) {
      stage((tt + 2) * 64, tt & 1);                // 8 loads into freed buffer
      asm volatile("s_waitcnt vmcnt(8)" ::: "memory");  // tile tt+1 (oldest 8) landed
      __builtin_amdgcn_s_barrier();
    } else if (tt + 1 < NT) {
      asm volatile("s_waitcnt vmcnt(0)" ::: "memory");  // tail drain (once)
      __builtin_amdgcn_s_barrier();
    }
  }

  const int row_base = m0 + wm * 128;
  const int col_base = n0 + wn * 64;

  if constexpr (MODE == 3) {
    float* O = (float*)Out;
#pragma unroll
    for (int m = 0; m < 8; m++)
#pragma unroll
      for (int j = 0; j < 4; j++)
#pragma unroll
        for (int r = 0; r < 4; r++) {
          int row = row_base + (m >> 2) * 64 + (m & 3) * 16 + quad * 4 + r;
          int col = col_base + j * 16 + lm;
          O[(size_t)row * DDIM + col] = acc[m][j][r];
        }
  } else if constexpr (MODE == 2) {
    bf16* O = (bf16*)Out;
#pragma unroll
    for (int m = 0; m < 8; m++) {
      int row = row_base + (m >> 2) * 64 + (m & 3) * 16 + quad * 4;
      int b = row >> 11, s = row & (S_LEN - 1);
#pragma unroll
      for (int j = 0; j < 4; j++) {
        int col = col_base + j * 16 + lm;
        int head = col >> 7, h = col & (HDIM - 1);
        bf16x4 pk;
#pragma unroll
        for (int r = 0; r < 4; r++) pk[r] = (bf16)acc[m][j][r];
        *(bf16x4*)&O[((size_t)(b * NHEAD + head) * HDIM + h) * S_LEN + s] = pk;
      }
    }
  } else {
    bf16* O = (bf16*)Out;
#pragma unroll
    for (int m = 0; m < 8; m++)
#pragma unroll
      for (int j = 0; j < 4; j++)
#pragma unroll
        for (int r = 0; r < 4; r++) {
          int row = row_base + (m >> 2) * 64 + (m & 3) * 16 + quad * 4 + r;
          int col = col_base + j * 16 + lm;
          int b = row >> 11, s = row & (S_LEN - 1);
          int head = col >> 7, h = col & (HDIM - 1);
          float v = acc[m][j][r];
          float partner = __shfl_xor(v, 1, 64);
          float inv_ts = __expf((float)(h >> 1) * -0.14391156831f);
          float ang = (float)s * inv_ts;
          float sn, cs;
          __sincosf(ang, &sn, &cs);
          float o = ((h & 1) == 0) ? (v * cs - partner * sn) : (v * cs + partner * sn);
          if (MODE == 0) o *= 0.08838834764831845f;
          O[((size_t)(b * NHEAD + head) * S_LEN + s) * HDIM + h] = (bf16)o;
        }
  }
}

// Flash attention, causal, block-cooperative LDS staging (round-1 structure,
// scaled to 8 waves / 512 threads): block = one head, lo rows [128a,128a+128)
// + hi rows [2048-128a-128, 2048-128a); wave w owns 16 lo + 16 hi rows.
// K/V tile staged once per block; staged tiles/head drop 784 -> 400.
// Chunked XCD swizzle co-locates all 8 sibling blocks of a head on one XCD
// so each head's K/V enters exactly one L2.
__global__ __launch_bounds__(512, 4)
void attn_kernel(const bf16* __restrict__ Q, const bf16* __restrict__ K,
                 const bf16* __restrict__ Vt, bf16* __restrict__ Aout) {
  __shared__ bf16 Ks[32 * KPAD];
  __shared__ bf16 Vs[128 * VPAD];
  __shared__ bf16 Pl[8][32 * PPAD];
  const int t    = threadIdx.x;
  const int lane = t & 63;
  const int wave = t >> 6;                       // 0..7
  const int quad = lane >> 4;
  const int lm   = lane & 15;
  const int lin    = blockIdx.y * 8 + blockIdx.x;      // 0..511
  const int newlin = (lin & 7) * 64 + (lin >> 3);      // chunked: head's 8 blocks on 1 XCD
  const int a    = newlin & 7;                   // 0..7
  const int bh   = newlin >> 3;                  // 0..63 = b*16+n
  const int lobase = a * 128 + wave * 16;
  const int hibase = 2048 - a * 128 - 128 + wave * 16;
  const size_t hb = (size_t)bh * S_LEN * HDIM;
  const bf16* Qh = Q + hb;
  const bf16* Kh = K + hb;
  const bf16* Vh = Vt + hb;
  bf16* P = &Pl[wave][0];

  bf16x8 qflo[4], qfhi[4];
#pragma unroll
  for (int c = 0; c < 4; c++) {
    qflo[c] = *(const bf16x8*)&Qh[(size_t)(lobase + lm) * HDIM + c * 32 + quad * 8];
    qfhi[c] = *(const bf16x8*)&Qh[(size_t)(hibase + lm) * HDIM + c * 32 + quad * 8];
  }

  bf16 onev = (bf16)1.0f;
  bf16x8 ones = {onev, onev, onev, onev, onev, onev, onev, onev};

  f32x4 olo[8], ohi[8];
#pragma unroll
  for (int hc = 0; hc < 8; hc++) {
    olo[hc] = (f32x4){0.f, 0.f, 0.f, 0.f};
    ohi[hc] = (f32x4){0.f, 0.f, 0.f, 0.f};
  }
  f32x4 llo = (f32x4){0.f, 0.f, 0.f, 0.f};
  f32x4 lhi = (f32x4){0.f, 0.f, 0.f, 0.f};

  const int nkt = 64 - 4 * a;                    // tiles staged by this block
  const int nlo = 4 * a + (wave >> 1) + 1;       // lo-active tile count
  const int nhi = 61 - 4 * a + (wave >> 1);      // hi-active tile count

  // staging: thread t copies 1 contiguous 16B chunk of K and of V
  const int krow0 = t >> 4, kcol0 = (t & 15) * 8;   // K: 32 rows x 16 chunks
  const int vrow0 = t >> 2, vcol0 = (t & 3) * 8;    // V: 128 rows x 4 chunks

  for (int kt = 0; kt < nkt; kt++) {
    const int kb = kt * 32;
    __syncthreads();   // previous tile's readers done
    {
      const bf16* kg = &Kh[(size_t)(kb + krow0) * HDIM + kcol0];
      *(bf16x8*)&Ks[krow0 * KPAD + kcol0] = *(const bf16x8*)kg;
      const bf16* vg = &Vh[(size_t)vrow0 * S_LEN + kb + vcol0];
      *(bf16x8*)&Vs[vrow0 * VPAD + vcol0] = *(const bf16x8*)vg;
    }
    __syncthreads();

    const bool hi_act = kt < nhi;
    const bool lo_act = kt < nlo;

    bf16x8 af[2][4];
#pragma unroll
    for (int cb = 0; cb < 2; cb++)
#pragma unroll
      for (int c = 0; c < 4; c++)
        af[cb][c] = *(const bf16x8*)&Ks[(cb * 16 + lm) * KPAD + c * 32 + quad * 8];

    if (hi_act) {
      f32x4 s[2] = {(f32x4){0.f, 0.f, 0.f, 0.f}, (f32x4){0.f, 0.f, 0.f, 0.f}};
#pragma unroll
      for (int c = 0; c < 4; c++)
#pragma unroll
        for (int cb = 0; cb < 2; cb++)
          s[cb] = __builtin_amdgcn_mfma_f32_16x16x32_bf16(af[cb][c], qfhi[c], s[cb], 0, 0, 0);
#pragma unroll
      for (int cb = 0; cb < 2; cb++) {
        bf16x4 pk;
#pragma unroll
        for (int r = 0; r < 4; r++) {
          int key = kb + cb * 16 + quad * 4 + r;
          float sv = (key <= hibase + lm) ? s[cb][r] : -3.0e38f;
          pk[r] = (bf16)__expf(sv - 12.0f);
        }
        *(bf16x4*)&P[(16 + lm) * PPAD + cb * 16 + quad * 4] = pk;
      }
    }
    if (lo_act) {
      f32x4 s[2] = {(f32x4){0.f, 0.f, 0.f, 0.f}, (f32x4){0.f, 0.f, 0.f, 0.f}};
#pragma unroll
      for (int c = 0; c < 4; c++)
#pragma unroll
        for (int cb = 0; cb < 2; cb++)
          s[cb] = __builtin_amdgcn_mfma_f32_16x16x32_bf16(af[cb][c], qflo[c], s[cb], 0, 0, 0);
#pragma unroll
      for (int cb = 0; cb < 2; cb++) {
        bf16x4 pk;
#pragma unroll
        for (int r = 0; r < 4; r++) {
          int key = kb + cb * 16 + quad * 4 + r;
          float sv = (key <= lobase + lm) ? s[cb][r] : -3.0e38f;
          pk[r] = (bf16)__expf(sv - 12.0f);
        }
        *(bf16x4*)&P[lm * PPAD + cb * 16 + quad * 4] = pk;
      }
    }
    __builtin_amdgcn_s_waitcnt(0xC07F);  // lgkmcnt(0): P visible to own wave

    bf16x8 vf[8];
#pragma unroll
    for (int hc = 0; hc < 8; hc++)
      vf[hc] = *(const bf16x8*)&Vs[(hc * 16 + lm) * VPAD + quad * 8];

    if (hi_act) {
      bf16x8 pf = *(const bf16x8*)&P[(16 + lm) * PPAD + quad * 8];
#pragma unroll
      for (int hc = 0; hc < 8; hc++)
        ohi[hc] = __builtin_amdgcn_mfma_f32_16x16x32_bf16(pf, vf[hc], ohi[hc], 0, 0, 0);
      lhi = __builtin_amdgcn_mfma_f32_16x16x32_bf16(pf, ones, lhi, 0, 0, 0);
    }
    if (lo_act) {
      bf16x8 pf = *(const bf16x8*)&P[lm * PPAD + quad * 8];
#pragma unroll
      for (int hc = 0; hc < 8; hc++)
        olo[hc] = __builtin_amdgcn_mfma_f32_16x16x32_bf16(pf, vf[hc], olo[hc], 0, 0, 0);
      llo = __builtin_amdgcn_mfma_f32_16x16x32_bf16(pf, ones, llo, 0, 0, 0);
    }
  }

  const int b = bh >> 4, n = bh & 15;
#pragma unroll
  for (int r = 0; r < 4; r++) {
    float invl = 1.0f / llo[r];
    float invh = 1.0f / lhi[r];
    int ql = lobase + quad * 4 + r;
    int qh = hibase + quad * 4 + r;
    size_t bl = ((size_t)(b * S_LEN + ql) * NHEAD + n) * HDIM;
    size_t bhh = ((size_t)(b * S_LEN + qh) * NHEAD + n) * HDIM;
#pragma unroll
    for (int hc = 0; hc < 8; hc++) {
      Aout[bl  + hc * 16 + lm] = (bf16)(olo[hc][r] * invl);
      Aout[bhh + hc * 16 + lm] = (bf16)(ohi[hc][r] * invh);
    }
  }
}

extern "C" void kernel_launch(void* const* d_in, const int* in_sizes, int n_in,
                              void* d_out, int out_size, void* d_ws, size_t ws_size,
                              hipStream_t stream) {
  const float* x  = (const float*)d_in[0];
  const float* wq = (const float*)d_in[1];
  const float* wk = (const float*)d_in[2];
  const float* wv = (const float*)d_in[3];
  const float* wo = (const float*)d_in[4];
  float* out = (float*)d_out;

  const size_t SZ  = (size_t)BATCH * S_LEN * NHEAD * HDIM;  // 16,777,216
  const size_t WSZ = (size_t)DDIM * DDIM;                   // 4,194,304
  bf16* Qb = (bf16*)d_ws;
  bf16* Kb = Qb + SZ;
  bf16* Vb = Kb + SZ;
  bf16* Eb = Vb + SZ;   // phase 1: x bf16; phase 2: attention output

  bf16* WTq = (bf16*)d_out;     // d_out doubles as scratch; final GEMM overwrites
  bf16* WTk = WTq + WSZ;
  bf16* WTv = WTk + WSZ;
  bf16* WTo = (bf16*)Qb;        // Qb free after attention

  dim3 blk(256);
  conv_kernel<<<SZ / (256 * 8), blk, 0, stream>>>(x, Eb);
  dim3 gt(32, 32);
  twconv_kernel<<<gt, blk, 0, stream>>>(wq, WTq);
  twconv_kernel<<<gt, blk, 0, stream>>>(wk, WTk);
  twconv_kernel<<<gt, blk, 0, stream>>>(wv, WTv);

  dim3 blk2(512);
  dim3 gg(DDIM / 256, (BATCH * S_LEN) / 256);   // (8, 32) = 256 blocks, 1/CU
  gemm_kernel<0><<<gg, blk2, 0, stream>>>(Eb, WTq, (void*)Qb);
  gemm_kernel<1><<<gg, blk2, 0, stream>>>(Eb, WTk, (void*)Kb);
  gemm_kernel<2><<<gg, blk2, 0, stream>>>(Eb, WTv, (void*)Vb);

  dim3 ga(8, BATCH * NHEAD);
  attn_kernel<<<ga, blk2, 0, stream>>>(Qb, Kb, Vb, Eb);

  twconv_kernel<<<gt, blk, 0, stream>>>(wo, WTo);
  gemm_kernel<3><<<gg, blk2, 0, stream>>>(Eb, WTo, (void*)out);
}

// Round 4
// 598.845 us; speedup vs baseline: 1.6145x; 1.6145x over previous
//
#include <hip/hip_runtime.h>
#include <hip/hip_bf16.h>
#include <cmath>

#define S_LEN 2048
#define DDIM  2048
#define NHEAD 16
#define HDIM  128
#define BATCH 4
#define KPAD  152  // K LDS row: 128 + 24
#define VPAD  40   // V LDS row: 32 + 8
#define PPAD  40   // P LDS row: 32 + 8

typedef __bf16 bf16;
typedef __attribute__((ext_vector_type(8))) __bf16 bf16x8;
typedef __attribute__((ext_vector_type(4))) __bf16 bf16x4;
typedef __attribute__((ext_vector_type(4))) float  f32x4;

__device__ __forceinline__ void gl_lds(const bf16* g, bf16* l) {
  __builtin_amdgcn_global_load_lds((const __attribute__((address_space(1))) unsigned*)g,
                                   (__attribute__((address_space(3))) unsigned*)l, 16, 0, 0);
}

__global__ __launch_bounds__(256)
void conv_kernel(const float* __restrict__ x, bf16* __restrict__ y) {
  size_t i = ((size_t)blockIdx.x * 256 + threadIdx.x) * 8;
  float4 a = *(const float4*)&x[i];
  float4 b = *(const float4*)&x[i + 4];
  bf16x8 o;
  o[0] = (bf16)a.x; o[1] = (bf16)a.y; o[2] = (bf16)a.z; o[3] = (bf16)a.w;
  o[4] = (bf16)b.x; o[5] = (bf16)b.y; o[6] = (bf16)b.z; o[7] = (bf16)b.w;
  *(bf16x8*)&y[i] = o;
}

// W f32 [2048][2048] -> Wt bf16 [n][k]
__global__ __launch_bounds__(256)
void twconv_kernel(const float* __restrict__ W, bf16* __restrict__ Wt) {
  __shared__ bf16 tile[64][72];
  const int t  = threadIdx.x;
  const int k0 = blockIdx.x * 64;
  const int n0 = blockIdx.y * 64;
#pragma unroll
  for (int it = 0; it < 4; it++) {
    int k = (t >> 4) + it * 16;
    int n = (t & 15) * 4;
    float4 v = *(const float4*)&W[(size_t)(k0 + k) * DDIM + n0 + n];
    tile[k][n + 0] = (bf16)v.x; tile[k][n + 1] = (bf16)v.y;
    tile[k][n + 2] = (bf16)v.z; tile[k][n + 3] = (bf16)v.w;
  }
  __syncthreads();
#pragma unroll
  for (int it = 0; it < 2; it++) {
    int n  = (t >> 3) + it * 32;
    int kc = (t & 7) * 8;
    bf16x8 o;
#pragma unroll
    for (int j = 0; j < 8; j++) o[j] = tile[kc + j][n];
    *(bf16x8*)&Wt[(size_t)(n0 + n) * DDIM + k0 + kc] = o;
  }
}

// 256x256-tile GEMM (round-1 structure), BK=64, 8 waves (2M x 4N),
// double-buffered LDS (128 KiB), counted vmcnt(8): next tile's
// global_load_lds stay in flight across barriers; never drained mid-loop.
// MODE: 0=Q(RoPE+scale), 1=K(RoPE), 2=V(transposed [b][n][h][s]), 3=OUT(f32)
template <int MODE>
__global__ __launch_bounds__(512, 2)
void gemm_kernel(const bf16* __restrict__ A, const bf16* __restrict__ Bt,
                 void* __restrict__ Out) {
  __shared__ bf16 As[2][256 * 64];
  __shared__ bf16 Bs[2][256 * 64];

  const int t    = threadIdx.x;
  const int m0   = blockIdx.y * 256;
  const int n0   = blockIdx.x * 256;
  const int lane = t & 63;
  const int wave = t >> 6;          // 0..7
  const int wm   = wave >> 2;       // 0..1  (M half)
  const int wn   = wave & 3;        // 0..3  (N quarter)
  const int quad = lane >> 4;
  const int lm   = lane & 15;
  const int sw   = lm & 7;

  const int lrow   = lane >> 3;     // 0..7
  const int lslot  = lane & 7;
  const int lchunk = lslot ^ lrow;  // pre-swizzled global chunk

  const int rA = wm * 128 + wn * 32;
  const int rB = (wn >> 1) * 128 + (wm * 2 + (wn & 1)) * 32;
  const bf16* gA = &A [(size_t)(m0 + rA + lrow) * DDIM + lchunk * 8];
  const bf16* gB = &Bt[(size_t)(n0 + rB + lrow) * DDIM + lchunk * 8];

  f32x4 acc[8][4];
#pragma unroll
  for (int i = 0; i < 8; i++)
#pragma unroll
    for (int j = 0; j < 4; j++) acc[i][j] = (f32x4){0.f, 0.f, 0.f, 0.f};

  auto stage = [&](int k0, int b) {
#pragma unroll
    for (int q = 0; q < 4; q++) {
      gl_lds(gA + (size_t)q * 8 * DDIM + k0, &As[b][(rA + q * 8) * 64]);
      gl_lds(gB + (size_t)q * 8 * DDIM + k0, &Bs[b][(rB + q * 8) * 64]);
    }
  };

  stage(0, 0);
  stage(64, 1);
  asm volatile("s_waitcnt vmcnt(8)" ::: "memory");  // tile 0 landed; tile 1 in flight
  __builtin_amdgcn_s_barrier();

  const int NT = DDIM / 64;  // 32
#pragma unroll 2
  for (int tt = 0; tt < NT; ++tt) {
    const bf16* as = &As[tt & 1][0];
    const bf16* bs = &Bs[tt & 1][0];
    bf16x8 af[4], bfr[4];

    // phase 0: K-slice 0, M-half 0
#pragma unroll
    for (int j = 0; j < 4; j++)
      bfr[j] = *(const bf16x8*)&bs[(wn * 64 + j * 16 + lm) * 64 + 8 * (quad ^ sw)];
#pragma unroll
    for (int i = 0; i < 4; i++)
      af[i] = *(const bf16x8*)&as[(wm * 128 + i * 16 + lm) * 64 + 8 * (quad ^ sw)];
    __builtin_amdgcn_s_setprio(1);
#pragma unroll
    for (int i = 0; i < 4; i++)
#pragma unroll
      for (int j = 0; j < 4; j++)
        acc[i][j] = __builtin_amdgcn_mfma_f32_16x16x32_bf16(af[i], bfr[j], acc[i][j], 0, 0, 0);
    __builtin_amdgcn_s_setprio(0);
    __builtin_amdgcn_sched_barrier(0);

    // phase 1: K-slice 0, M-half 1 (reuses bfr)
#pragma unroll
    for (int i = 0; i < 4; i++)
      af[i] = *(const bf16x8*)&as[(wm * 128 + 64 + i * 16 + lm) * 64 + 8 * (quad ^ sw)];
    __builtin_amdgcn_s_setprio(1);
#pragma unroll
    for (int i = 0; i < 4; i++)
#pragma unroll
      for (int j = 0; j < 4; j++)
        acc[4 + i][j] = __builtin_amdgcn_mfma_f32_16x16x32_bf16(af[i], bfr[j], acc[4 + i][j], 0, 0, 0);
    __builtin_amdgcn_s_setprio(0);
    __builtin_amdgcn_sched_barrier(0);

    // phase 2: K-slice 1, M-half 0
#pragma unroll
    for (int j = 0; j < 4; j++)
      bfr[j] = *(const bf16x8*)&bs[(wn * 64 + j * 16 + lm) * 64 + 8 * ((4 + quad) ^ sw)];
#pragma unroll
    for (int i = 0; i < 4; i++)
      af[i] = *(const bf16x8*)&as[(wm * 128 + i * 16 + lm) * 64 + 8 * ((4 + quad) ^ sw)];
    __builtin_amdgcn_s_setprio(1);
#pragma unroll
    for (int i = 0; i < 4; i++)
#pragma unroll
      for (int j = 0; j < 4; j++)
        acc[i][j] = __builtin_amdgcn_mfma_f32_16x16x32_bf16(af[i], bfr[j], acc[i][j], 0, 0, 0);
    __builtin_amdgcn_s_setprio(0);
    __builtin_amdgcn_sched_barrier(0);

    // phase 3: K-slice 1, M-half 1
#pragma unroll
    for (int i = 0; i < 4; i++)
      af[i] = *(const bf16x8*)&as[(wm * 128 + 64 + i * 16 + lm) * 64 + 8 * ((4 + quad) ^ sw)];
    __builtin_amdgcn_s_setprio(1);
#pragma unroll
    for (int i = 0; i < 4; i++)
#pragma unroll
      for (int j = 0; j < 4; j++)
        acc[4 + i][j] = __builtin_amdgcn_mfma_f32_16x16x32_bf16(af[i], bfr[j], acc[4 + i][j], 0, 0, 0);
    __builtin_amdgcn_s_setprio(0);
    __builtin_amdgcn_sched_barrier(0);

    // tile boundary: free buf[tt&1], keep tile tt+1's loads in flight
    asm volatile("s_waitcnt lgkmcnt(0)" ::: "memory");
    __builtin_amdgcn_s_barrier();                  // all waves done reading buf[tt&1]
    if (tt + 2 < NT) {
      stage((tt + 2) * 64, tt & 1);                // 8 loads into freed buffer
      asm volatile("s_waitcnt vmcnt(8)" ::: "memory");  // tile tt+1 (oldest 8) landed
      __builtin_amdgcn_s_barrier();
    } else if (tt + 1 < NT) {
      asm volatile("s_waitcnt vmcnt(0)" ::: "memory");  // tail drain (once)
      __builtin_amdgcn_s_barrier();
    }
  }

  const int row_base = m0 + wm * 128;
  const int col_base = n0 + wn * 64;

  if constexpr (MODE == 3) {
    float* O = (float*)Out;
#pragma unroll
    for (int m = 0; m < 8; m++)
#pragma unroll
      for (int j = 0; j < 4; j++)
#pragma unroll
        for (int r = 0; r < 4; r++) {
          int row = row_base + (m >> 2) * 64 + (m & 3) * 16 + quad * 4 + r;
          int col = col_base + j * 16 + lm;
          O[(size_t)row * DDIM + col] = acc[m][j][r];
        }
  } else if constexpr (MODE == 2) {
    bf16* O = (bf16*)Out;
#pragma unroll
    for (int m = 0; m < 8; m++) {
      int row = row_base + (m >> 2) * 64 + (m & 3) * 16 + quad * 4;
      int b = row >> 11, s = row & (S_LEN - 1);
#pragma unroll
      for (int j = 0; j < 4; j++) {
        int col = col_base + j * 16 + lm;
        int head = col >> 7, h = col & (HDIM - 1);
        bf16x4 pk;
#pragma unroll
        for (int r = 0; r < 4; r++) pk[r] = (bf16)acc[m][j][r];
        *(bf16x4*)&O[((size_t)(b * NHEAD + head) * HDIM + h) * S_LEN + s] = pk;
      }
    }
  } else {
    bf16* O = (bf16*)Out;
#pragma unroll
    for (int m = 0; m < 8; m++)
#pragma unroll
      for (int j = 0; j < 4; j++)
#pragma unroll
        for (int r = 0; r < 4; r++) {
          int row = row_base + (m >> 2) * 64 + (m & 3) * 16 + quad * 4 + r;
          int col = col_base + j * 16 + lm;
          int b = row >> 11, s = row & (S_LEN - 1);
          int head = col >> 7, h = col & (HDIM - 1);
          float v = acc[m][j][r];
          float partner = __shfl_xor(v, 1, 64);
          float inv_ts = __expf((float)(h >> 1) * -0.14391156831f);
          float ang = (float)s * inv_ts;
          float sn, cs;
          __sincosf(ang, &sn, &cs);
          float o = ((h & 1) == 0) ? (v * cs - partner * sn) : (v * cs + partner * sn);
          if (MODE == 0) o *= 0.08838834764831845f;
          O[((size_t)(b * NHEAD + head) * S_LEN + s) * HDIM + h] = (bf16)o;
        }
  }
}

// Flash attention, causal, block-cooperative LDS staging, 8 waves/block.
// Block = one head, lo rows [128a,128a+128) + hi rows mirrored; wave w owns
// 16 lo + 16 hi rows. K/V tile staged once per block (400 tiles/head vs 784
// at 4-wave). Chunked XCD swizzle (dispatch = lin%8 round-robin, m09) pins a
// head's 8 lockstep siblings to one XCD/L2. a-order within each head is
// pair-balanced {0,7,1,6,2,5,3,4} so consecutive block pairs sum to 100 tiles.
// launch_bounds(512,2): VGPR cap ~128 >= the ~88 this structure needs (r3's
// (512,4) capped at 64 -> 1.1 GB scratch spill).
__global__ __launch_bounds__(512, 2)
void attn_kernel(const bf16* __restrict__ Q, const bf16* __restrict__ K,
                 const bf16* __restrict__ Vt, bf16* __restrict__ Aout) {
  __shared__ bf16 Ks[32 * KPAD];
  __shared__ bf16 Vs[128 * VPAD];
  __shared__ bf16 Pl[8][32 * PPAD];
  const int t    = threadIdx.x;
  const int lane = t & 63;
  const int wave = t >> 6;                       // 0..7
  const int quad = lane >> 4;
  const int lm   = lane & 15;
  const int lin  = blockIdx.y * 8 + blockIdx.x;  // 0..511
  const int xcd  = lin & 7;                      // dispatch round-robin -> XCD
  const int j    = lin >> 3;                     // 0..63 within XCD
  const int bh   = xcd * 8 + (j >> 3);           // head: 8 heads per XCD
  const int ja   = j & 7;
  const int a    = (ja & 1) ? (7 - (ja >> 1)) : (ja >> 1);  // pair-balanced
  const int lobase = a * 128 + wave * 16;
  const int hibase = 2048 - a * 128 - 128 + wave * 16;
  const size_t hb = (size_t)bh * S_LEN * HDIM;
  const bf16* Qh = Q + hb;
  const bf16* Kh = K + hb;
  const bf16* Vh = Vt + hb;
  bf16* P = &Pl[wave][0];

  bf16x8 qflo[4], qfhi[4];
#pragma unroll
  for (int c = 0; c < 4; c++) {
    qflo[c] = *(const bf16x8*)&Qh[(size_t)(lobase + lm) * HDIM + c * 32 + quad * 8];
    qfhi[c] = *(const bf16x8*)&Qh[(size_t)(hibase + lm) * HDIM + c * 32 + quad * 8];
  }

  bf16 onev = (bf16)1.0f;
  bf16x8 ones = {onev, onev, onev, onev, onev, onev, onev, onev};

  f32x4 olo[8], ohi[8];
#pragma unroll
  for (int hc = 0; hc < 8; hc++) {
    olo[hc] = (f32x4){0.f, 0.f, 0.f, 0.f};
    ohi[hc] = (f32x4){0.f, 0.f, 0.f, 0.f};
  }
  f32x4 llo = (f32x4){0.f, 0.f, 0.f, 0.f};
  f32x4 lhi = (f32x4){0.f, 0.f, 0.f, 0.f};

  const int nkt = 64 - 4 * a;                    // tiles staged by this block
  const int nlo = 4 * a + (wave >> 1) + 1;       // lo-active tile count
  const int nhi = 61 - 4 * a + (wave >> 1);      // hi-active tile count

  // staging: thread t copies 1 contiguous 16B chunk of K and of V
  const int krow0 = t >> 4, kcol0 = (t & 15) * 8;   // K: 32 rows x 16 chunks
  const int vrow0 = t >> 2, vcol0 = (t & 3) * 8;    // V: 128 rows x 4 chunks

  for (int kt = 0; kt < nkt; kt++) {
    const int kb = kt * 32;
    __syncthreads();   // previous tile's readers done
    {
      const bf16* kg = &Kh[(size_t)(kb + krow0) * HDIM + kcol0];
      *(bf16x8*)&Ks[krow0 * KPAD + kcol0] = *(const bf16x8*)kg;
      const bf16* vg = &Vh[(size_t)vrow0 * S_LEN + kb + vcol0];
      *(bf16x8*)&Vs[vrow0 * VPAD + vcol0] = *(const bf16x8*)vg;
    }
    __syncthreads();

    const bool hi_act = kt < nhi;
    const bool lo_act = kt < nlo;

    bf16x8 af[2][4];
#pragma unroll
    for (int cb = 0; cb < 2; cb++)
#pragma unroll
      for (int c = 0; c < 4; c++)
        af[cb][c] = *(const bf16x8*)&Ks[(cb * 16 + lm) * KPAD + c * 32 + quad * 8];

    if (hi_act) {
      f32x4 s[2] = {(f32x4){0.f, 0.f, 0.f, 0.f}, (f32x4){0.f, 0.f, 0.f, 0.f}};
#pragma unroll
      for (int c = 0; c < 4; c++)
#pragma unroll
        for (int cb = 0; cb < 2; cb++)
          s[cb] = __builtin_amdgcn_mfma_f32_16x16x32_bf16(af[cb][c], qfhi[c], s[cb], 0, 0, 0);
#pragma unroll
      for (int cb = 0; cb < 2; cb++) {
        bf16x4 pk;
#pragma unroll
        for (int r = 0; r < 4; r++) {
          int key = kb + cb * 16 + quad * 4 + r;
          float sv = (key <= hibase + lm) ? s[cb][r] : -3.0e38f;
          pk[r] = (bf16)__expf(sv - 12.0f);
        }
        *(bf16x4*)&P[(16 + lm) * PPAD + cb * 16 + quad * 4] = pk;
      }
    }
    if (lo_act) {
      f32x4 s[2] = {(f32x4){0.f, 0.f, 0.f, 0.f}, (f32x4){0.f, 0.f, 0.f, 0.f}};
#pragma unroll
      for (int c = 0; c < 4; c++)
#pragma unroll
        for (int cb = 0; cb < 2; cb++)
          s[cb] = __builtin_amdgcn_mfma_f32_16x16x32_bf16(af[cb][c], qflo[c], s[cb], 0, 0, 0);
#pragma unroll
      for (int cb = 0; cb < 2; cb++) {
        bf16x4 pk;
#pragma unroll
        for (int r = 0; r < 4; r++) {
          int key = kb + cb * 16 + quad * 4 + r;
          float sv = (key <= lobase + lm) ? s[cb][r] : -3.0e38f;
          pk[r] = (bf16)__expf(sv - 12.0f);
        }
        *(bf16x4*)&P[lm * PPAD + cb * 16 + quad * 4] = pk;
      }
    }
    __builtin_amdgcn_s_waitcnt(0xC07F);  // lgkmcnt(0): P visible to own wave

    bf16x8 vf[8];
#pragma unroll
    for (int hc = 0; hc < 8; hc++)
      vf[hc] = *(const bf16x8*)&Vs[(hc * 16 + lm) * VPAD + quad * 8];

    if (hi_act) {
      bf16x8 pf = *(const bf16x8*)&P[(16 + lm) * PPAD + quad * 8];
#pragma unroll
      for (int hc = 0; hc < 8; hc++)
        ohi[hc] = __builtin_amdgcn_mfma_f32_16x16x32_bf16(pf, vf[hc], ohi[hc], 0, 0, 0);
      lhi = __builtin_amdgcn_mfma_f32_16x16x32_bf16(pf, ones, lhi, 0, 0, 0);
    }
    if (lo_act) {
      bf16x8 pf = *(const bf16x8*)&P[lm * PPAD + quad * 8];
#pragma unroll
      for (int hc = 0; hc < 8; hc++)
        olo[hc] = __builtin_amdgcn_mfma_f32_16x16x32_bf16(pf, vf[hc], olo[hc], 0, 0, 0);
      llo = __builtin_amdgcn_mfma_f32_16x16x32_bf16(pf, ones, llo, 0, 0, 0);
    }
  }

  const int b = bh >> 4, n = bh & 15;
#pragma unroll
  for (int r = 0; r < 4; r++) {
    float invl = 1.0f / llo[r];
    float invh = 1.0f / lhi[r];
    int ql = lobase + quad * 4 + r;
    int qh = hibase + quad * 4 + r;
    size_t bl = ((size_t)(b * S_LEN + ql) * NHEAD + n) * HDIM;
    size_t bhh = ((size_t)(b * S_LEN + qh) * NHEAD + n) * HDIM;
#pragma unroll
    for (int hc = 0; hc < 8; hc++) {
      Aout[bl  + hc * 16 + lm] = (bf16)(olo[hc][r] * invl);
      Aout[bhh + hc * 16 + lm] = (bf16)(ohi[hc][r] * invh);
    }
  }
}

extern "C" void kernel_launch(void* const* d_in, const int* in_sizes, int n_in,
                              void* d_out, int out_size, void* d_ws, size_t ws_size,
                              hipStream_t stream) {
  const float* x  = (const float*)d_in[0];
  const float* wq = (const float*)d_in[1];
  const float* wk = (const float*)d_in[2];
  const float* wv = (const float*)d_in[3];
  const float* wo = (const float*)d_in[4];
  float* out = (float*)d_out;

  const size_t SZ  = (size_t)BATCH * S_LEN * NHEAD * HDIM;  // 16,777,216
  const size_t WSZ = (size_t)DDIM * DDIM;                   // 4,194,304
  bf16* Qb = (bf16*)d_ws;
  bf16* Kb = Qb + SZ;
  bf16* Vb = Kb + SZ;
  bf16* Eb = Vb + SZ;   // phase 1: x bf16; phase 2: attention output

  bf16* WTq = (bf16*)d_out;     // d_out doubles as scratch; final GEMM overwrites
  bf16* WTk = WTq + WSZ;
  bf16* WTv = WTk + WSZ;
  bf16* WTo = (bf16*)Qb;        // Qb free after attention

  dim3 blk(256);
  conv_kernel<<<SZ / (256 * 8), blk, 0, stream>>>(x, Eb);
  dim3 gt(32, 32);
  twconv_kernel<<<gt, blk, 0, stream>>>(wq, WTq);
  twconv_kernel<<<gt, blk, 0, stream>>>(wk, WTk);
  twconv_kernel<<<gt, blk, 0, stream>>>(wv, WTv);

  dim3 blk2(512);
  dim3 gg(DDIM / 256, (BATCH * S_LEN) / 256);   // (8, 32) = 256 blocks, 1/CU
  gemm_kernel<0><<<gg, blk2, 0, stream>>>(Eb, WTq, (void*)Qb);
  gemm_kernel<1><<<gg, blk2, 0, stream>>>(Eb, WTk, (void*)Kb);
  gemm_kernel<2><<<gg, blk2, 0, stream>>>(Eb, WTv, (void*)Vb);

  dim3 ga(8, BATCH * NHEAD);
  attn_kernel<<<ga, blk2, 0, stream>>>(Qb, Kb, Vb, Eb);

  twconv_kernel<<<gt, blk, 0, stream>>>(wo, WTo);
  gemm_kernel<3><<<gg, blk2, 0, stream>>>(Eb, WTo, (void*)out);
}

// Round 5
// 574.947 us; speedup vs baseline: 1.6816x; 1.0416x over previous
//
#include <hip/hip_runtime.h>
#include <hip/hip_bf16.h>
#include <cmath>

#define S_LEN 2048
#define DDIM  2048
#define NHEAD 16
#define HDIM  128
#define BATCH 4
#define KPAD  152  // K LDS row: 128 + 24
#define VPAD  40   // V LDS row: 32 + 8
#define PPAD  40   // P LDS row: 32 + 8

typedef __bf16 bf16;
typedef __attribute__((ext_vector_type(8))) __bf16 bf16x8;
typedef __attribute__((ext_vector_type(4))) __bf16 bf16x4;
typedef __attribute__((ext_vector_type(4))) float  f32x4;

__device__ __forceinline__ void gl_lds(const bf16* g, bf16* l) {
  __builtin_amdgcn_global_load_lds((const __attribute__((address_space(1))) unsigned*)g,
                                   (__attribute__((address_space(3))) unsigned*)l, 16, 0, 0);
}

__global__ __launch_bounds__(256)
void conv_kernel(const float* __restrict__ x, bf16* __restrict__ y) {
  size_t i = ((size_t)blockIdx.x * 256 + threadIdx.x) * 8;
  float4 a = *(const float4*)&x[i];
  float4 b = *(const float4*)&x[i + 4];
  bf16x8 o;
  o[0] = (bf16)a.x; o[1] = (bf16)a.y; o[2] = (bf16)a.z; o[3] = (bf16)a.w;
  o[4] = (bf16)b.x; o[5] = (bf16)b.y; o[6] = (bf16)b.z; o[7] = (bf16)b.w;
  *(bf16x8*)&y[i] = o;
}

// W f32 [2048][2048] -> Wt bf16 [n][k]
__global__ __launch_bounds__(256)
void twconv_kernel(const float* __restrict__ W, bf16* __restrict__ Wt) {
  __shared__ bf16 tile[64][72];
  const int t  = threadIdx.x;
  const int k0 = blockIdx.x * 64;
  const int n0 = blockIdx.y * 64;
#pragma unroll
  for (int it = 0; it < 4; it++) {
    int k = (t >> 4) + it * 16;
    int n = (t & 15) * 4;
    float4 v = *(const float4*)&W[(size_t)(k0 + k) * DDIM + n0 + n];
    tile[k][n + 0] = (bf16)v.x; tile[k][n + 1] = (bf16)v.y;
    tile[k][n + 2] = (bf16)v.z; tile[k][n + 3] = (bf16)v.w;
  }
  __syncthreads();
#pragma unroll
  for (int it = 0; it < 2; it++) {
    int n  = (t >> 3) + it * 32;
    int kc = (t & 7) * 8;
    bf16x8 o;
#pragma unroll
    for (int j = 0; j < 8; j++) o[j] = tile[kc + j][n];
    *(bf16x8*)&Wt[(size_t)(n0 + n) * DDIM + k0 + kc] = o;
  }
}

// 256x256-tile GEMM (round-1 structure), BK=64, 8 waves (2M x 4N),
// double-buffered LDS (128 KiB), counted vmcnt(8): next tile's
// global_load_lds stay in flight across barriers; never drained mid-loop.
// MODE: 0=Q(RoPE+scale), 1=K(RoPE), 2=V(transposed [b][n][h][s]), 3=OUT(f32)
template <int MODE>
__global__ __launch_bounds__(512, 2)
void gemm_kernel(const bf16* __restrict__ A, const bf16* __restrict__ Bt,
                 void* __restrict__ Out) {
  __shared__ bf16 As[2][256 * 64];
  __shared__ bf16 Bs[2][256 * 64];

  const int t    = threadIdx.x;
  const int m0   = blockIdx.y * 256;
  const int n0   = blockIdx.x * 256;
  const int lane = t & 63;
  const int wave = t >> 6;          // 0..7
  const int wm   = wave >> 2;       // 0..1  (M half)
  const int wn   = wave & 3;        // 0..3  (N quarter)
  const int quad = lane >> 4;
  const int lm   = lane & 15;
  const int sw   = lm & 7;

  const int lrow   = lane >> 3;     // 0..7
  const int lslot  = lane & 7;
  const int lchunk = lslot ^ lrow;  // pre-swizzled global chunk

  const int rA = wm * 128 + wn * 32;
  const int rB = (wn >> 1) * 128 + (wm * 2 + (wn & 1)) * 32;
  const bf16* gA = &A [(size_t)(m0 + rA + lrow) * DDIM + lchunk * 8];
  const bf16* gB = &Bt[(size_t)(n0 + rB + lrow) * DDIM + lchunk * 8];

  f32x4 acc[8][4];
#pragma unroll
  for (int i = 0; i < 8; i++)
#pragma unroll
    for (int j = 0; j < 4; j++) acc[i][j] = (f32x4){0.f, 0.f, 0.f, 0.f};

  auto stage = [&](int k0, int b) {
#pragma unroll
    for (int q = 0; q < 4; q++) {
      gl_lds(gA + (size_t)q * 8 * DDIM + k0, &As[b][(rA + q * 8) * 64]);
      gl_lds(gB + (size_t)q * 8 * DDIM + k0, &Bs[b][(rB + q * 8) * 64]);
    }
  };

  stage(0, 0);
  stage(64, 1);
  asm volatile("s_waitcnt vmcnt(8)" ::: "memory");  // tile 0 landed; tile 1 in flight
  __builtin_amdgcn_s_barrier();

  const int NT = DDIM / 64;  // 32
#pragma unroll 2
  for (int tt = 0; tt < NT; ++tt) {
    const bf16* as = &As[tt & 1][0];
    const bf16* bs = &Bs[tt & 1][0];
    bf16x8 af[4], bfr[4];

    // phase 0: K-slice 0, M-half 0
#pragma unroll
    for (int j = 0; j < 4; j++)
      bfr[j] = *(const bf16x8*)&bs[(wn * 64 + j * 16 + lm) * 64 + 8 * (quad ^ sw)];
#pragma unroll
    for (int i = 0; i < 4; i++)
      af[i] = *(const bf16x8*)&as[(wm * 128 + i * 16 + lm) * 64 + 8 * (quad ^ sw)];
    __builtin_amdgcn_s_setprio(1);
#pragma unroll
    for (int i = 0; i < 4; i++)
#pragma unroll
      for (int j = 0; j < 4; j++)
        acc[i][j] = __builtin_amdgcn_mfma_f32_16x16x32_bf16(af[i], bfr[j], acc[i][j], 0, 0, 0);
    __builtin_amdgcn_s_setprio(0);
    __builtin_amdgcn_sched_barrier(0);

    // phase 1: K-slice 0, M-half 1 (reuses bfr)
#pragma unroll
    for (int i = 0; i < 4; i++)
      af[i] = *(const bf16x8*)&as[(wm * 128 + 64 + i * 16 + lm) * 64 + 8 * (quad ^ sw)];
    __builtin_amdgcn_s_setprio(1);
#pragma unroll
    for (int i = 0; i < 4; i++)
#pragma unroll
      for (int j = 0; j < 4; j++)
        acc[4 + i][j] = __builtin_amdgcn_mfma_f32_16x16x32_bf16(af[i], bfr[j], acc[4 + i][j], 0, 0, 0);
    __builtin_amdgcn_s_setprio(0);
    __builtin_amdgcn_sched_barrier(0);

    // phase 2: K-slice 1, M-half 0
#pragma unroll
    for (int j = 0; j < 4; j++)
      bfr[j] = *(const bf16x8*)&bs[(wn * 64 + j * 16 + lm) * 64 + 8 * ((4 + quad) ^ sw)];
#pragma unroll
    for (int i = 0; i < 4; i++)
      af[i] = *(const bf16x8*)&as[(wm * 128 + i * 16 + lm) * 64 + 8 * ((4 + quad) ^ sw)];
    __builtin_amdgcn_s_setprio(1);
#pragma unroll
    for (int i = 0; i < 4; i++)
#pragma unroll
      for (int j = 0; j < 4; j++)
        acc[i][j] = __builtin_amdgcn_mfma_f32_16x16x32_bf16(af[i], bfr[j], acc[i][j], 0, 0, 0);
    __builtin_amdgcn_s_setprio(0);
    __builtin_amdgcn_sched_barrier(0);

    // phase 3: K-slice 1, M-half 1
#pragma unroll
    for (int i = 0; i < 4; i++)
      af[i] = *(const bf16x8*)&as[(wm * 128 + 64 + i * 16 + lm) * 64 + 8 * ((4 + quad) ^ sw)];
    __builtin_amdgcn_s_setprio(1);
#pragma unroll
    for (int i = 0; i < 4; i++)
#pragma unroll
      for (int j = 0; j < 4; j++)
        acc[4 + i][j] = __builtin_amdgcn_mfma_f32_16x16x32_bf16(af[i], bfr[j], acc[4 + i][j], 0, 0, 0);
    __builtin_amdgcn_s_setprio(0);
    __builtin_amdgcn_sched_barrier(0);

    // tile boundary: free buf[tt&1], keep tile tt+1's loads in flight
    asm volatile("s_waitcnt lgkmcnt(0)" ::: "memory");
    __builtin_amdgcn_s_barrier();                  // all waves done reading buf[tt&1]
    if (tt + 2 < NT) {
      stage((tt + 2) * 64, tt & 1);                // 8 loads into freed buffer
      asm volatile("s_waitcnt vmcnt(8)" ::: "memory");  // tile tt+1 (oldest 8) landed
      __builtin_amdgcn_s_barrier();
    } else if (tt + 1 < NT) {
      asm volatile("s_waitcnt vmcnt(0)" ::: "memory");  // tail drain (once)
      __builtin_amdgcn_s_barrier();
    }
  }

  const int row_base = m0 + wm * 128;
  const int col_base = n0 + wn * 64;

  if constexpr (MODE == 3) {
    float* O = (float*)Out;
#pragma unroll
    for (int m = 0; m < 8; m++)
#pragma unroll
      for (int j = 0; j < 4; j++)
#pragma unroll
        for (int r = 0; r < 4; r++) {
          int row = row_base + (m >> 2) * 64 + (m & 3) * 16 + quad * 4 + r;
          int col = col_base + j * 16 + lm;
          O[(size_t)row * DDIM + col] = acc[m][j][r];
        }
  } else if constexpr (MODE == 2) {
    bf16* O = (bf16*)Out;
#pragma unroll
    for (int m = 0; m < 8; m++) {
      int row = row_base + (m >> 2) * 64 + (m & 3) * 16 + quad * 4;
      int b = row >> 11, s = row & (S_LEN - 1);
#pragma unroll
      for (int j = 0; j < 4; j++) {
        int col = col_base + j * 16 + lm;
        int head = col >> 7, h = col & (HDIM - 1);
        bf16x4 pk;
#pragma unroll
        for (int r = 0; r < 4; r++) pk[r] = (bf16)acc[m][j][r];
        *(bf16x4*)&O[((size_t)(b * NHEAD + head) * HDIM + h) * S_LEN + s] = pk;
      }
    }
  } else {
    bf16* O = (bf16*)Out;
#pragma unroll
    for (int m = 0; m < 8; m++)
#pragma unroll
      for (int j = 0; j < 4; j++)
#pragma unroll
        for (int r = 0; r < 4; r++) {
          int row = row_base + (m >> 2) * 64 + (m & 3) * 16 + quad * 4 + r;
          int col = col_base + j * 16 + lm;
          int b = row >> 11, s = row & (S_LEN - 1);
          int head = col >> 7, h = col & (HDIM - 1);
          float v = acc[m][j][r];
          float partner = __shfl_xor(v, 1, 64);
          float inv_ts = __expf((float)(h >> 1) * -0.14391156831f);
          float ang = (float)s * inv_ts;
          float sn, cs;
          __sincosf(ang, &sn, &cs);
          float o = ((h & 1) == 0) ? (v * cs - partner * sn) : (v * cs + partner * sn);
          if (MODE == 0) o *= 0.08838834764831845f;
          O[((size_t)(b * NHEAD + head) * S_LEN + s) * HDIM + h] = (bf16)o;
        }
  }
}

// Flash attention, causal, 8 waves/block, XCD-pinned (round-4 structure) +
// double-buffered K/V with register prefetch (T14), ONE barrier per tile:
//   iter kt: stw regs(tile kt+1)->buf[(kt+1)&1]; ldk tile kt+2 -> regs;
//            compute tile kt from buf[kt&1]; __syncthreads().
// Round-2's version of this regressed via L2 thrash (570 MB fetch, unpinned
// siblings); round-4's XCD pinning fixed that regime (49 MB fetch), so the
// latency-hiding mechanism is retested here. vf (V-frag) reads issued before
// the exp/P-write block so LDS latency hides under VALU.
__global__ __launch_bounds__(512, 2)
void attn_kernel(const bf16* __restrict__ Q, const bf16* __restrict__ K,
                 const bf16* __restrict__ Vt, bf16* __restrict__ Aout) {
  __shared__ bf16 Ks[2][32 * KPAD];
  __shared__ bf16 Vs[2][128 * VPAD];
  __shared__ bf16 Pl[8][32 * PPAD];
  const int t    = threadIdx.x;
  const int lane = t & 63;
  const int wave = t >> 6;                       // 0..7
  const int quad = lane >> 4;
  const int lm   = lane & 15;
  const int lin  = blockIdx.y * 8 + blockIdx.x;  // 0..511
  const int xcd  = lin & 7;                      // dispatch round-robin -> XCD
  const int j    = lin >> 3;                     // 0..63 within XCD
  const int bh   = xcd * 8 + (j >> 3);           // head: 8 heads per XCD
  const int ja   = j & 7;
  const int a    = (ja & 1) ? (7 - (ja >> 1)) : (ja >> 1);  // pair-balanced
  const int lobase = a * 128 + wave * 16;
  const int hibase = 2048 - a * 128 - 128 + wave * 16;
  const size_t hb = (size_t)bh * S_LEN * HDIM;
  const bf16* Qh = Q + hb;
  const bf16* Kh = K + hb;
  const bf16* Vh = Vt + hb;
  bf16* P = &Pl[wave][0];

  bf16x8 qflo[4], qfhi[4];
#pragma unroll
  for (int c = 0; c < 4; c++) {
    qflo[c] = *(const bf16x8*)&Qh[(size_t)(lobase + lm) * HDIM + c * 32 + quad * 8];
    qfhi[c] = *(const bf16x8*)&Qh[(size_t)(hibase + lm) * HDIM + c * 32 + quad * 8];
  }

  bf16 onev = (bf16)1.0f;
  bf16x8 ones = {onev, onev, onev, onev, onev, onev, onev, onev};

  f32x4 olo[8], ohi[8];
#pragma unroll
  for (int hc = 0; hc < 8; hc++) {
    olo[hc] = (f32x4){0.f, 0.f, 0.f, 0.f};
    ohi[hc] = (f32x4){0.f, 0.f, 0.f, 0.f};
  }
  f32x4 llo = (f32x4){0.f, 0.f, 0.f, 0.f};
  f32x4 lhi = (f32x4){0.f, 0.f, 0.f, 0.f};

  const int nkt = 64 - 4 * a;                    // tiles staged by this block
  const int nlo = 4 * a + (wave >> 1) + 1;       // lo-active tile count
  const int nhi = 61 - 4 * a + (wave >> 1);      // hi-active tile count

  // staging: thread t handles 1 contiguous 16B chunk of K and of V
  const int krow0 = t >> 4, kcol0 = (t & 15) * 8;   // K: 32 rows x 16 chunks
  const int vrow0 = t >> 2, vcol0 = (t & 3) * 8;    // V: 128 rows x 4 chunks

  bf16x8 kr, vr;   // prefetch registers (one tile in flight)

  auto ldk = [&](int kt) {
    kr = *(const bf16x8*)&Kh[(size_t)(kt * 32 + krow0) * HDIM + kcol0];
    vr = *(const bf16x8*)&Vh[(size_t)vrow0 * S_LEN + kt * 32 + vcol0];
  };
  auto stw = [&](int b) {
    *(bf16x8*)&Ks[b][krow0 * KPAD + kcol0] = kr;
    *(bf16x8*)&Vs[b][vrow0 * VPAD + vcol0] = vr;
  };

  // prologue: tile 0 -> LDS buf0; tile 1 -> regs
  ldk(0);
  stw(0);
  if (nkt > 1) ldk(1);
  __syncthreads();

  for (int kt = 0; kt < nkt; kt++) {
    const int kb  = kt * 32;
    const int cur = kt & 1;

    if (kt + 1 < nkt) stw((kt + 1) & 1);   // ds_write next tile (regs -> LDS)
    if (kt + 2 < nkt) ldk(kt + 2);         // issue global loads 2 tiles ahead

    const bool hi_act = kt < nhi;
    const bool lo_act = kt < nlo;

    bf16x8 af[2][4];
#pragma unroll
    for (int cb = 0; cb < 2; cb++)
#pragma unroll
      for (int c = 0; c < 4; c++)
        af[cb][c] = *(const bf16x8*)&Ks[cur][(cb * 16 + lm) * KPAD + c * 32 + quad * 8];

    f32x4 shi[2] = {(f32x4){0.f, 0.f, 0.f, 0.f}, (f32x4){0.f, 0.f, 0.f, 0.f}};
    f32x4 slo[2] = {(f32x4){0.f, 0.f, 0.f, 0.f}, (f32x4){0.f, 0.f, 0.f, 0.f}};
    if (hi_act) {
#pragma unroll
      for (int c = 0; c < 4; c++)
#pragma unroll
        for (int cb = 0; cb < 2; cb++)
          shi[cb] = __builtin_amdgcn_mfma_f32_16x16x32_bf16(af[cb][c], qfhi[c], shi[cb], 0, 0, 0);
    }
    if (lo_act) {
#pragma unroll
      for (int c = 0; c < 4; c++)
#pragma unroll
        for (int cb = 0; cb < 2; cb++)
          slo[cb] = __builtin_amdgcn_mfma_f32_16x16x32_bf16(af[cb][c], qflo[c], slo[cb], 0, 0, 0);
    }

    // V fragments issued early: LDS latency hides under the exp/P VALU work
    bf16x8 vf[8];
#pragma unroll
    for (int hc = 0; hc < 8; hc++)
      vf[hc] = *(const bf16x8*)&Vs[cur][(hc * 16 + lm) * VPAD + quad * 8];

    if (hi_act) {
#pragma unroll
      for (int cb = 0; cb < 2; cb++) {
        bf16x4 pk;
#pragma unroll
        for (int r = 0; r < 4; r++) {
          int key = kb + cb * 16 + quad * 4 + r;
          float sv = (key <= hibase + lm) ? shi[cb][r] : -3.0e38f;
          pk[r] = (bf16)__expf(sv - 12.0f);
        }
        *(bf16x4*)&P[(16 + lm) * PPAD + cb * 16 + quad * 4] = pk;
      }
    }
    if (lo_act) {
#pragma unroll
      for (int cb = 0; cb < 2; cb++) {
        bf16x4 pk;
#pragma unroll
        for (int r = 0; r < 4; r++) {
          int key = kb + cb * 16 + quad * 4 + r;
          float sv = (key <= lobase + lm) ? slo[cb][r] : -3.0e38f;
          pk[r] = (bf16)__expf(sv - 12.0f);
        }
        *(bf16x4*)&P[lm * PPAD + cb * 16 + quad * 4] = pk;
      }
    }
    __builtin_amdgcn_s_waitcnt(0xC07F);  // lgkmcnt(0): P visible to own wave

    if (hi_act) {
      bf16x8 pf = *(const bf16x8*)&P[(16 + lm) * PPAD + quad * 8];
#pragma unroll
      for (int hc = 0; hc < 8; hc++)
        ohi[hc] = __builtin_amdgcn_mfma_f32_16x16x32_bf16(pf, vf[hc], ohi[hc], 0, 0, 0);
      lhi = __builtin_amdgcn_mfma_f32_16x16x32_bf16(pf, ones, lhi, 0, 0, 0);
    }
    if (lo_act) {
      bf16x8 pf = *(const bf16x8*)&P[lm * PPAD + quad * 8];
#pragma unroll
      for (int hc = 0; hc < 8; hc++)
        olo[hc] = __builtin_amdgcn_mfma_f32_16x16x32_bf16(pf, vf[hc], olo[hc], 0, 0, 0);
      llo = __builtin_amdgcn_mfma_f32_16x16x32_bf16(pf, ones, llo, 0, 0, 0);
    }
    __syncthreads();   // writers of buf[(kt+1)&1] done AND readers of buf[kt&1] done
  }

  const int b = bh >> 4, n = bh & 15;
#pragma unroll
  for (int r = 0; r < 4; r++) {
    float invl = 1.0f / llo[r];
    float invh = 1.0f / lhi[r];
    int ql = lobase + quad * 4 + r;
    int qh = hibase + quad * 4 + r;
    size_t bl = ((size_t)(b * S_LEN + ql) * NHEAD + n) * HDIM;
    size_t bhh = ((size_t)(b * S_LEN + qh) * NHEAD + n) * HDIM;
#pragma unroll
    for (int hc = 0; hc < 8; hc++) {
      Aout[bl  + hc * 16 + lm] = (bf16)(olo[hc][r] * invl);
      Aout[bhh + hc * 16 + lm] = (bf16)(ohi[hc][r] * invh);
    }
  }
}

extern "C" void kernel_launch(void* const* d_in, const int* in_sizes, int n_in,
                              void* d_out, int out_size, void* d_ws, size_t ws_size,
                              hipStream_t stream) {
  const float* x  = (const float*)d_in[0];
  const float* wq = (const float*)d_in[1];
  const float* wk = (const float*)d_in[2];
  const float* wv = (const float*)d_in[3];
  const float* wo = (const float*)d_in[4];
  float* out = (float*)d_out;

  const size_t SZ  = (size_t)BATCH * S_LEN * NHEAD * HDIM;  // 16,777,216
  const size_t WSZ = (size_t)DDIM * DDIM;                   // 4,194,304
  bf16* Qb = (bf16*)d_ws;
  bf16* Kb = Qb + SZ;
  bf16* Vb = Kb + SZ;
  bf16* Eb = Vb + SZ;   // phase 1: x bf16; phase 2: attention output

  bf16* WTq = (bf16*)d_out;     // d_out doubles as scratch; final GEMM overwrites
  bf16* WTk = WTq + WSZ;
  bf16* WTv = WTk + WSZ;
  bf16* WTo = (bf16*)Qb;        // Qb free after attention

  dim3 blk(256);
  conv_kernel<<<SZ / (256 * 8), blk, 0, stream>>>(x, Eb);
  dim3 gt(32, 32);
  twconv_kernel<<<gt, blk, 0, stream>>>(wq, WTq);
  twconv_kernel<<<gt, blk, 0, stream>>>(wk, WTk);
  twconv_kernel<<<gt, blk, 0, stream>>>(wv, WTv);

  dim3 blk2(512);
  dim3 gg(DDIM / 256, (BATCH * S_LEN) / 256);   // (8, 32) = 256 blocks, 1/CU
  gemm_kernel<0><<<gg, blk2, 0, stream>>>(Eb, WTq, (void*)Qb);
  gemm_kernel<1><<<gg, blk2, 0, stream>>>(Eb, WTk, (void*)Kb);
  gemm_kernel<2><<<gg, blk2, 0, stream>>>(Eb, WTv, (void*)Vb);

  dim3 ga(8, BATCH * NHEAD);
  attn_kernel<<<ga, blk2, 0, stream>>>(Qb, Kb, Vb, Eb);

  twconv_kernel<<<gt, blk, 0, stream>>>(wo, WTo);
  gemm_kernel<3><<<gg, blk2, 0, stream>>>(Eb, WTo, (void*)out);
}

// Round 6
// 573.767 us; speedup vs baseline: 1.6851x; 1.0021x over previous
//
#include <hip/hip_runtime.h>
#include <hip/hip_bf16.h>
#include <cmath>

#define S_LEN 2048
#define DDIM  2048
#define NHEAD 16
#define HDIM  128
#define BATCH 4
#define KPAD  152  // K LDS row: 128 + 24
#define VPAD  40   // V LDS row: 32 + 8
#define PPAD  40   // P LDS row: 32 + 8

typedef __bf16 bf16;
typedef __attribute__((ext_vector_type(8))) __bf16 bf16x8;
typedef __attribute__((ext_vector_type(4))) __bf16 bf16x4;
typedef __attribute__((ext_vector_type(4))) float  f32x4;

__device__ __forceinline__ void gl_lds(const bf16* g, bf16* l) {
  __builtin_amdgcn_global_load_lds((const __attribute__((address_space(1))) unsigned*)g,
                                   (__attribute__((address_space(3))) unsigned*)l, 16, 0, 0);
}

__global__ __launch_bounds__(256)
void conv_kernel(const float* __restrict__ x, bf16* __restrict__ y) {
  size_t i = ((size_t)blockIdx.x * 256 + threadIdx.x) * 8;
  float4 a = *(const float4*)&x[i];
  float4 b = *(const float4*)&x[i + 4];
  bf16x8 o;
  o[0] = (bf16)a.x; o[1] = (bf16)a.y; o[2] = (bf16)a.z; o[3] = (bf16)a.w;
  o[4] = (bf16)b.x; o[5] = (bf16)b.y; o[6] = (bf16)b.z; o[7] = (bf16)b.w;
  *(bf16x8*)&y[i] = o;
}

// W f32 [2048][2048] -> Wt bf16 [n][k]
__global__ __launch_bounds__(256)
void twconv_kernel(const float* __restrict__ W, bf16* __restrict__ Wt) {
  __shared__ bf16 tile[64][72];
  const int t  = threadIdx.x;
  const int k0 = blockIdx.x * 64;
  const int n0 = blockIdx.y * 64;
#pragma unroll
  for (int it = 0; it < 4; it++) {
    int k = (t >> 4) + it * 16;
    int n = (t & 15) * 4;
    float4 v = *(const float4*)&W[(size_t)(k0 + k) * DDIM + n0 + n];
    tile[k][n + 0] = (bf16)v.x; tile[k][n + 1] = (bf16)v.y;
    tile[k][n + 2] = (bf16)v.z; tile[k][n + 3] = (bf16)v.w;
  }
  __syncthreads();
#pragma unroll
  for (int it = 0; it < 2; it++) {
    int n  = (t >> 3) + it * 32;
    int kc = (t & 7) * 8;
    bf16x8 o;
#pragma unroll
    for (int j = 0; j < 8; j++) o[j] = tile[kc + j][n];
    *(bf16x8*)&Wt[(size_t)(n0 + n) * DDIM + k0 + kc] = o;
  }
}

// 256x256-tile GEMM, BK=32, 8 waves (2M x 4N), 4-slot LDS ring (128 KiB).
// Fine-phase counted-vmcnt schedule (T3+T4+T5): per K-tile, 2 phases of
// {ds_reads ∥ 2 global_load_lds -> barrier -> lgkmcnt(0) -> setprio(1) ->
// 16 MFMA -> setprio(0)}, then {vmcnt(8); barrier}. Tile T computes from
// slot T%4 while staging T+3 into slot (T+3)%4 (= slot of T-1, already
// read -> overwrite-safe). vmcnt(8) retires exactly tile T+1's 4 loads
// (issued 3 tiles earlier); never drains to 0 mid-loop. BK=32 rows (64 B)
// are bank-conflict-free without swizzle (group = quad + 4*(row&1)).
// MODE: 0=Q(RoPE+scale), 1=K(RoPE), 2=V(transposed [b][n][h][s]), 3=OUT(f32)
template <int MODE>
__global__ __launch_bounds__(512, 2)
void gemm_kernel(const bf16* __restrict__ A, const bf16* __restrict__ Bt,
                 void* __restrict__ Out) {
  __shared__ bf16 As[4][256 * 32];
  __shared__ bf16 Bs[4][256 * 32];

  const int t    = threadIdx.x;
  const int m0   = blockIdx.y * 256;
  const int n0   = blockIdx.x * 256;
  const int lane = t & 63;
  const int wave = t >> 6;          // 0..7
  const int wm   = wave >> 2;       // 0..1  (M half)
  const int wn   = wave & 3;        // 0..3  (N quarter)
  const int quad = lane >> 4;
  const int lm   = lane & 15;

  // staging: thread t covers row t>>2 (and +128), k-chunk (t&3)*8
  const int srow   = t >> 2;        // 0..127
  const int schunk = (t & 3) * 8;

  f32x4 acc[8][4];
#pragma unroll
  for (int i = 0; i < 8; i++)
#pragma unroll
    for (int j = 0; j < 4; j++) acc[i][j] = (f32x4){0.f, 0.f, 0.f, 0.f};

  auto stageA = [&](int T) {
    const int slot = T & 3;
    const int k0   = T * 32;
    gl_lds(&A[(size_t)(m0 + srow) * DDIM + k0 + schunk],       &As[slot][(16 * wave) * 32]);
    gl_lds(&A[(size_t)(m0 + 128 + srow) * DDIM + k0 + schunk], &As[slot][(128 + 16 * wave) * 32]);
  };
  auto stageB = [&](int T) {
    const int slot = T & 3;
    const int k0   = T * 32;
    gl_lds(&Bt[(size_t)(n0 + srow) * DDIM + k0 + schunk],       &Bs[slot][(16 * wave) * 32]);
    gl_lds(&Bt[(size_t)(n0 + 128 + srow) * DDIM + k0 + schunk], &Bs[slot][(128 + 16 * wave) * 32]);
  };

  // prologue: stage tiles 0,1,2 (12 loads); retire tile 0 only (keep 8 in flight)
  stageA(0); stageB(0);
  stageA(1); stageB(1);
  stageA(2); stageB(2);
  asm volatile("s_waitcnt vmcnt(8)" ::: "memory");
  __builtin_amdgcn_s_barrier();

  const int NT = DDIM / 32;  // 64
  bf16x8 bfr[4];

#pragma unroll 1
  for (int T = 0; T < NT; ++T) {
    const int slot = T & 3;
    const bf16* as = &As[slot][0];
    const bf16* bs = &Bs[slot][0];
    bf16x8 af[4];

    // ---- phase 0: M-half 0 (reads B + A-half0; stages next A) ----
#pragma unroll
    for (int j = 0; j < 4; j++)
      bfr[j] = *(const bf16x8*)&bs[(wn * 64 + j * 16 + lm) * 32 + quad * 8];
#pragma unroll
    for (int i = 0; i < 4; i++)
      af[i] = *(const bf16x8*)&as[(wm * 128 + i * 16 + lm) * 32 + quad * 8];
    if (T + 3 < NT) stageA(T + 3);
    __builtin_amdgcn_s_barrier();
    asm volatile("s_waitcnt lgkmcnt(0)" ::: "memory");
    __builtin_amdgcn_s_setprio(1);
#pragma unroll
    for (int i = 0; i < 4; i++)
#pragma unroll
      for (int j = 0; j < 4; j++)
        acc[i][j] = __builtin_amdgcn_mfma_f32_16x16x32_bf16(af[i], bfr[j], acc[i][j], 0, 0, 0);
    __builtin_amdgcn_s_setprio(0);
    __builtin_amdgcn_sched_barrier(0);

    // ---- phase 1: M-half 1 (reads A-half1; reuses bfr; stages next B) ----
#pragma unroll
    for (int i = 0; i < 4; i++)
      af[i] = *(const bf16x8*)&as[(wm * 128 + 64 + i * 16 + lm) * 32 + quad * 8];
    if (T + 3 < NT) stageB(T + 3);
    __builtin_amdgcn_s_barrier();
    asm volatile("s_waitcnt lgkmcnt(0)" ::: "memory");
    __builtin_amdgcn_s_setprio(1);
#pragma unroll
    for (int i = 0; i < 4; i++)
#pragma unroll
      for (int j = 0; j < 4; j++)
        acc[4 + i][j] = __builtin_amdgcn_mfma_f32_16x16x32_bf16(af[i], bfr[j], acc[4 + i][j], 0, 0, 0);
    __builtin_amdgcn_s_setprio(0);
    __builtin_amdgcn_sched_barrier(0);

    // ---- K-tile boundary: retire tile T+1's stages, keep 8 in flight ----
    if (T < NT - 3) {
      asm volatile("s_waitcnt vmcnt(8)" ::: "memory");
    } else if (T == NT - 3) {
      asm volatile("s_waitcnt vmcnt(4)" ::: "memory");
    } else if (T == NT - 2) {
      asm volatile("s_waitcnt vmcnt(0)" ::: "memory");
    }
    if (T < NT - 1) __builtin_amdgcn_s_barrier();
  }

  const int row_base = m0 + wm * 128;
  const int col_base = n0 + wn * 64;

  if constexpr (MODE == 3) {
    float* O = (float*)Out;
#pragma unroll
    for (int m = 0; m < 8; m++)
#pragma unroll
      for (int j = 0; j < 4; j++)
#pragma unroll
        for (int r = 0; r < 4; r++) {
          int row = row_base + (m >> 2) * 64 + (m & 3) * 16 + quad * 4 + r;
          int col = col_base + j * 16 + lm;
          O[(size_t)row * DDIM + col] = acc[m][j][r];
        }
  } else if constexpr (MODE == 2) {
    bf16* O = (bf16*)Out;
#pragma unroll
    for (int m = 0; m < 8; m++) {
      int row = row_base + (m >> 2) * 64 + (m & 3) * 16 + quad * 4;
      int b = row >> 11, s = row & (S_LEN - 1);
#pragma unroll
      for (int j = 0; j < 4; j++) {
        int col = col_base + j * 16 + lm;
        int head = col >> 7, h = col & (HDIM - 1);
        bf16x4 pk;
#pragma unroll
        for (int r = 0; r < 4; r++) pk[r] = (bf16)acc[m][j][r];
        *(bf16x4*)&O[((size_t)(b * NHEAD + head) * HDIM + h) * S_LEN + s] = pk;
      }
    }
  } else {
    bf16* O = (bf16*)Out;
#pragma unroll
    for (int m = 0; m < 8; m++)
#pragma unroll
      for (int j = 0; j < 4; j++)
#pragma unroll
        for (int r = 0; r < 4; r++) {
          int row = row_base + (m >> 2) * 64 + (m & 3) * 16 + quad * 4 + r;
          int col = col_base + j * 16 + lm;
          int b = row >> 11, s = row & (S_LEN - 1);
          int head = col >> 7, h = col & (HDIM - 1);
          float v = acc[m][j][r];
          float partner = __shfl_xor(v, 1, 64);
          float inv_ts = __expf((float)(h >> 1) * -0.14391156831f);
          float ang = (float)s * inv_ts;
          float sn, cs;
          __sincosf(ang, &sn, &cs);
          float o = ((h & 1) == 0) ? (v * cs - partner * sn) : (v * cs + partner * sn);
          if (MODE == 0) o *= 0.08838834764831845f;
          O[((size_t)(b * NHEAD + head) * S_LEN + s) * HDIM + h] = (bf16)o;
        }
  }
}

// Flash attention, causal, 8 waves/block, XCD-pinned (round-4 structure) +
// double-buffered K/V with register prefetch (T14), ONE barrier per tile:
//   iter kt: stw regs(tile kt+1)->buf[(kt+1)&1]; ldk tile kt+2 -> regs;
//            compute tile kt from buf[kt&1]; __syncthreads().
// vf (V-frag) reads issued before the exp/P-write block so LDS latency
// hides under VALU. XCD pinning keeps each head's K/V in one L2 (49 MB fetch).
__global__ __launch_bounds__(512, 2)
void attn_kernel(const bf16* __restrict__ Q, const bf16* __restrict__ K,
                 const bf16* __restrict__ Vt, bf16* __restrict__ Aout) {
  __shared__ bf16 Ks[2][32 * KPAD];
  __shared__ bf16 Vs[2][128 * VPAD];
  __shared__ bf16 Pl[8][32 * PPAD];
  const int t    = threadIdx.x;
  const int lane = t & 63;
  const int wave = t >> 6;                       // 0..7
  const int quad = lane >> 4;
  const int lm   = lane & 15;
  const int lin  = blockIdx.y * 8 + blockIdx.x;  // 0..511
  const int xcd  = lin & 7;                      // dispatch round-robin -> XCD
  const int j    = lin >> 3;                     // 0..63 within XCD
  const int bh   = xcd * 8 + (j >> 3);           // head: 8 heads per XCD
  const int ja   = j & 7;
  const int a    = (ja & 1) ? (7 - (ja >> 1)) : (ja >> 1);  // pair-balanced
  const int lobase = a * 128 + wave * 16;
  const int hibase = 2048 - a * 128 - 128 + wave * 16;
  const size_t hb = (size_t)bh * S_LEN * HDIM;
  const bf16* Qh = Q + hb;
  const bf16* Kh = K + hb;
  const bf16* Vh = Vt + hb;
  bf16* P = &Pl[wave][0];

  bf16x8 qflo[4], qfhi[4];
#pragma unroll
  for (int c = 0; c < 4; c++) {
    qflo[c] = *(const bf16x8*)&Qh[(size_t)(lobase + lm) * HDIM + c * 32 + quad * 8];
    qfhi[c] = *(const bf16x8*)&Qh[(size_t)(hibase + lm) * HDIM + c * 32 + quad * 8];
  }

  bf16 onev = (bf16)1.0f;
  bf16x8 ones = {onev, onev, onev, onev, onev, onev, onev, onev};

  f32x4 olo[8], ohi[8];
#pragma unroll
  for (int hc = 0; hc < 8; hc++) {
    olo[hc] = (f32x4){0.f, 0.f, 0.f, 0.f};
    ohi[hc] = (f32x4){0.f, 0.f, 0.f, 0.f};
  }
  f32x4 llo = (f32x4){0.f, 0.f, 0.f, 0.f};
  f32x4 lhi = (f32x4){0.f, 0.f, 0.f, 0.f};

  const int nkt = 64 - 4 * a;                    // tiles staged by this block
  const int nlo = 4 * a + (wave >> 1) + 1;       // lo-active tile count
  const int nhi = 61 - 4 * a + (wave >> 1);      // hi-active tile count

  // staging: thread t handles 1 contiguous 16B chunk of K and of V
  const int krow0 = t >> 4, kcol0 = (t & 15) * 8;   // K: 32 rows x 16 chunks
  const int vrow0 = t >> 2, vcol0 = (t & 3) * 8;    // V: 128 rows x 4 chunks

  bf16x8 kr, vr;   // prefetch registers (one tile in flight)

  auto ldk = [&](int kt) {
    kr = *(const bf16x8*)&Kh[(size_t)(kt * 32 + krow0) * HDIM + kcol0];
    vr = *(const bf16x8*)&Vh[(size_t)vrow0 * S_LEN + kt * 32 + vcol0];
  };
  auto stw = [&](int b) {
    *(bf16x8*)&Ks[b][krow0 * KPAD + kcol0] = kr;
    *(bf16x8*)&Vs[b][vrow0 * VPAD + vcol0] = vr;
  };

  // prologue: tile 0 -> LDS buf0; tile 1 -> regs
  ldk(0);
  stw(0);
  if (nkt > 1) ldk(1);
  __syncthreads();

  for (int kt = 0; kt < nkt; kt++) {
    const int kb  = kt * 32;
    const int cur = kt & 1;

    if (kt + 1 < nkt) stw((kt + 1) & 1);   // ds_write next tile (regs -> LDS)
    if (kt + 2 < nkt) ldk(kt + 2);         // issue global loads 2 tiles ahead

    const bool hi_act = kt < nhi;
    const bool lo_act = kt < nlo;

    bf16x8 af[2][4];
#pragma unroll
    for (int cb = 0; cb < 2; cb++)
#pragma unroll
      for (int c = 0; c < 4; c++)
        af[cb][c] = *(const bf16x8*)&Ks[cur][(cb * 16 + lm) * KPAD + c * 32 + quad * 8];

    f32x4 shi[2] = {(f32x4){0.f, 0.f, 0.f, 0.f}, (f32x4){0.f, 0.f, 0.f, 0.f}};
    f32x4 slo[2] = {(f32x4){0.f, 0.f, 0.f, 0.f}, (f32x4){0.f, 0.f, 0.f, 0.f}};
    if (hi_act) {
#pragma unroll
      for (int c = 0; c < 4; c++)
#pragma unroll
        for (int cb = 0; cb < 2; cb++)
          shi[cb] = __builtin_amdgcn_mfma_f32_16x16x32_bf16(af[cb][c], qfhi[c], shi[cb], 0, 0, 0);
    }
    if (lo_act) {
#pragma unroll
      for (int c = 0; c < 4; c++)
#pragma unroll
        for (int cb = 0; cb < 2; cb++)
          slo[cb] = __builtin_amdgcn_mfma_f32_16x16x32_bf16(af[cb][c], qflo[c], slo[cb], 0, 0, 0);
    }

    // V fragments issued early: LDS latency hides under the exp/P VALU work
    bf16x8 vf[8];
#pragma unroll
    for (int hc = 0; hc < 8; hc++)
      vf[hc] = *(const bf16x8*)&Vs[cur][(hc * 16 + lm) * VPAD + quad * 8];

    if (hi_act) {
#pragma unroll
      for (int cb = 0; cb < 2; cb++) {
        bf16x4 pk;
#pragma unroll
        for (int r = 0; r < 4; r++) {
          int key = kb + cb * 16 + quad * 4 + r;
          float sv = (key <= hibase + lm) ? shi[cb][r] : -3.0e38f;
          pk[r] = (bf16)__expf(sv - 12.0f);
        }
        *(bf16x4*)&P[(16 + lm) * PPAD + cb * 16 + quad * 4] = pk;
      }
    }
    if (lo_act) {
#pragma unroll
      for (int cb = 0; cb < 2; cb++) {
        bf16x4 pk;
#pragma unroll
        for (int r = 0; r < 4; r++) {
          int key = kb + cb * 16 + quad * 4 + r;
          float sv = (key <= lobase + lm) ? slo[cb][r] : -3.0e38f;
          pk[r] = (bf16)__expf(sv - 12.0f);
        }
        *(bf16x4*)&P[lm * PPAD + cb * 16 + quad * 4] = pk;
      }
    }
    __builtin_amdgcn_s_waitcnt(0xC07F);  // lgkmcnt(0): P visible to own wave

    if (hi_act) {
      bf16x8 pf = *(const bf16x8*)&P[(16 + lm) * PPAD + quad * 8];
#pragma unroll
      for (int hc = 0; hc < 8; hc++)
        ohi[hc] = __builtin_amdgcn_mfma_f32_16x16x32_bf16(pf, vf[hc], ohi[hc], 0, 0, 0);
      lhi = __builtin_amdgcn_mfma_f32_16x16x32_bf16(pf, ones, lhi, 0, 0, 0);
    }
    if (lo_act) {
      bf16x8 pf = *(const bf16x8*)&P[lm * PPAD + quad * 8];
#pragma unroll
      for (int hc = 0; hc < 8; hc++)
        olo[hc] = __builtin_amdgcn_mfma_f32_16x16x32_bf16(pf, vf[hc], olo[hc], 0, 0, 0);
      llo = __builtin_amdgcn_mfma_f32_16x16x32_bf16(pf, ones, llo, 0, 0, 0);
    }
    __syncthreads();   // writers of buf[(kt+1)&1] done AND readers of buf[kt&1] done
  }

  const int b = bh >> 4, n = bh & 15;
#pragma unroll
  for (int r = 0; r < 4; r++) {
    float invl = 1.0f / llo[r];
    float invh = 1.0f / lhi[r];
    int ql = lobase + quad * 4 + r;
    int qh = hibase + quad * 4 + r;
    size_t bl = ((size_t)(b * S_LEN + ql) * NHEAD + n) * HDIM;
    size_t bhh = ((size_t)(b * S_LEN + qh) * NHEAD + n) * HDIM;
#pragma unroll
    for (int hc = 0; hc < 8; hc++) {
      Aout[bl  + hc * 16 + lm] = (bf16)(olo[hc][r] * invl);
      Aout[bhh + hc * 16 + lm] = (bf16)(ohi[hc][r] * invh);
    }
  }
}

extern "C" void kernel_launch(void* const* d_in, const int* in_sizes, int n_in,
                              void* d_out, int out_size, void* d_ws, size_t ws_size,
                              hipStream_t stream) {
  const float* x  = (const float*)d_in[0];
  const float* wq = (const float*)d_in[1];
  const float* wk = (const float*)d_in[2];
  const float* wv = (const float*)d_in[3];
  const float* wo = (const float*)d_in[4];
  float* out = (float*)d_out;

  const size_t SZ  = (size_t)BATCH * S_LEN * NHEAD * HDIM;  // 16,777,216
  const size_t WSZ = (size_t)DDIM * DDIM;                   // 4,194,304
  bf16* Qb = (bf16*)d_ws;
  bf16* Kb = Qb + SZ;
  bf16* Vb = Kb + SZ;
  bf16* Eb = Vb + SZ;   // phase 1: x bf16; phase 2: attention output

  bf16* WTq = (bf16*)d_out;     // d_out doubles as scratch; final GEMM overwrites
  bf16* WTk = WTq + WSZ;
  bf16* WTv = WTk + WSZ;
  bf16* WTo = (bf16*)Qb;        // Qb free after attention

  dim3 blk(256);
  conv_kernel<<<SZ / (256 * 8), blk, 0, stream>>>(x, Eb);
  dim3 gt(32, 32);
  twconv_kernel<<<gt, blk, 0, stream>>>(wq, WTq);
  twconv_kernel<<<gt, blk, 0, stream>>>(wk, WTk);
  twconv_kernel<<<gt, blk, 0, stream>>>(wv, WTv);

  dim3 blk2(512);
  dim3 gg(DDIM / 256, (BATCH * S_LEN) / 256);   // (8, 32) = 256 blocks, 1/CU
  gemm_kernel<0><<<gg, blk2, 0, stream>>>(Eb, WTq, (void*)Qb);
  gemm_kernel<1><<<gg, blk2, 0, stream>>>(Eb, WTk, (void*)Kb);
  gemm_kernel<2><<<gg, blk2, 0, stream>>>(Eb, WTv, (void*)Vb);

  dim3 ga(8, BATCH * NHEAD);
  attn_kernel<<<ga, blk2, 0, stream>>>(Qb, Kb, Vb, Eb);

  twconv_kernel<<<gt, blk, 0, stream>>>(wo, WTo);
  gemm_kernel<3><<<gg, blk2, 0, stream>>>(Eb, WTo, (void*)out);
}